// Round 1
// baseline (18911.113 us; speedup 1.0000x reference)
//
#include <hip/hip_runtime.h>
#include <cmath>

#define Bsz 256
#define Tn  100
#define Fd  128
#define Hd  512
#define Od  128
#define Md  512

__device__ __forceinline__ float sigf(float x) { return 1.0f / (1.0f + expf(-x)); }

// WcombT[f][hh] = sum_o Wfc[o][hh] * Wq[f][256+o]; bqxi[f] = sum_o b_fc[o] * Wq[f][256+o]
__global__ void kA(const float* __restrict__ Wfc, const float* __restrict__ Wq,
                   const float* __restrict__ bfc, float* __restrict__ WcombT,
                   float* __restrict__ bqxi)
{
    int bid = blockIdx.x;
    if (bid < 256) {
        int idx = bid * 256 + threadIdx.x;   // 65536 total
        int f = idx >> 9;                    // 0..127
        int hh = idx & 511;                  // 0..511
        float s = 0.f;
        for (int o = 0; o < Od; ++o)
            s += Wfc[o * Hd + hh] * Wq[f * 384 + 256 + o];
        WcombT[f * Hd + hh] = s;
    } else {
        int f = threadIdx.x;
        if (f < Fd) {
            float s = 0.f;
            for (int o = 0; o < Od; ++o) s += bfc[o] * Wq[f * 384 + 256 + o];
            bqxi[f] = s;
        }
    }
}

// Per-step: z/zp -> ls -> scores -> softmax -> gd.  One block per batch row.
__global__ void kS1(int t,
    const float* __restrict__ input, const float* __restrict__ Xmean,
    const float* __restrict__ Wgz, const float* __restrict__ bgz,
    const float* __restrict__ Wgzp, const float* __restrict__ bgzp,
    const float* __restrict__ Wq, const float* __restrict__ bq,
    const float* __restrict__ memory,
    const float* __restrict__ WcombT, const float* __restrict__ bqxi,
    const float* __restrict__ h_in, float* __restrict__ gd)
{
    __shared__ __align__(16) float h_s[Hd];
    __shared__ __align__(16) float zz[256];
    __shared__ __align__(16) float ls_s[Fd];
    __shared__ __align__(16) float sc[Md];
    __shared__ __align__(16) float tmp[256];

    int b = blockIdx.x, tid = threadIdx.x;   // 256 threads
    h_s[tid]       = h_in[b * Hd + tid];
    h_s[tid + 256] = h_in[b * Hd + tid + 256];

    // ---- z (tid<128) / zp (tid>=128) ----
    {
        int f = tid & 127;
        const float* base = input + (size_t)b * 6 * Tn * Fd + t * Fd;  // + ch*Tn*Fd
        float x    = base[0 * Tn * Fd + f];
        float mask = base[2 * Tn * Fd + f];
        float xm   = Xmean[t * Fd + f];
        float xl, dl, w, bb;
        if (tid < 128) { xl = base[1 * Tn * Fd + f]; dl = base[3 * Tn * Fd + f]; w = Wgz[f * 129];  bb = bgz[f]; }
        else           { xl = base[4 * Tn * Fd + f]; dl = base[5 * Tn * Fd + f]; w = Wgzp[f * 129]; bb = bgzp[f]; }
        float d = expf(-fmaxf(dl * w + bb, 0.f));
        zz[tid] = mask * x + (1.f - mask) * (d * xl + (1.f - d) * xm);
    }
    __syncthreads();

    // ---- ls = bq + bqxi + zz@Wq[:, :256]^T + h@Wcomb ----
    {
        float s;
        if (tid < 128) {
            int f = tid;
            s = bq[f] + bqxi[f];
            const float4* wq4 = (const float4*)(Wq + f * 384);
            const float4* z4  = (const float4*)zz;
            #pragma unroll 8
            for (int k = 0; k < 64; ++k) {
                float4 w = wq4[k], z = z4[k];
                s += w.x * z.x + w.y * z.y + w.z * z.z + w.w * z.w;
            }
        } else {
            int f = tid - 128;
            s = 0.f;
            const float4* wc4 = (const float4*)(WcombT + f * Hd);
            const float4* h4  = (const float4*)h_s;
            #pragma unroll 8
            for (int k = 0; k < 128; ++k) {
                float4 w = wc4[k], h = h4[k];
                s += w.x * h.x + w.y * h.y + w.z * h.z + w.w * h.w;
            }
        }
        tmp[tid] = s;
    }
    __syncthreads();
    if (tid < 128) ls_s[tid] = tmp[tid] + tmp[tid + 128];
    __syncthreads();

    // ---- scores = ls @ memory^T ----
    for (int m = tid; m < Md; m += 256) {
        const float4* mr = (const float4*)(memory + m * Fd);
        const float4* l4 = (const float4*)ls_s;
        float s = 0.f;
        #pragma unroll 8
        for (int k = 0; k < 32; ++k) {
            float4 w = mr[k], l = l4[k];
            s += w.x * l.x + w.y * l.y + w.z * l.z + w.w * l.w;
        }
        sc[m] = s;
    }
    __syncthreads();

    // ---- softmax over 512 ----
    tmp[tid] = fmaxf(sc[tid], sc[tid + 256]);
    __syncthreads();
    for (int s = 128; s > 0; s >>= 1) {
        if (tid < s) tmp[tid] = fmaxf(tmp[tid], tmp[tid + s]);
        __syncthreads();
    }
    float mx = tmp[0];
    __syncthreads();
    float e0 = expf(sc[tid] - mx), e1 = expf(sc[tid + 256] - mx);
    sc[tid] = e0; sc[tid + 256] = e1;
    tmp[tid] = e0 + e1;
    __syncthreads();
    for (int s = 128; s > 0; s >>= 1) {
        if (tid < s) tmp[tid] += tmp[tid + s];
        __syncthreads();
    }
    float inv = 1.0f / tmp[0];
    __syncthreads();

    // ---- gd = attn @ memory (normalization deferred via inv) ----
    {
        int f = tid & 127, half = tid >> 7;
        float s = 0.f;
        int m0 = half * 256;
        #pragma unroll 4
        for (int m = m0; m < m0 + 256; ++m)
            s += sc[m] * memory[m * Fd + f];
        tmp[tid] = s;
    }
    __syncthreads();
    if (tid < 128) gd[b * Fd + tid] = (tmp[tid] + tmp[tid + 128]) * inv;
}

// gates = gd@Wih^T + h@Whh^T + b; fused LSTM update.
// grid (8, 32): 32-row b-tile x 16-col j-tile (x4 gates => 64 n). 128 threads, 4x4 register tiles.
__global__ void kS2(const float* __restrict__ gd, const float* __restrict__ h_in,
                    float* __restrict__ h_out, float* __restrict__ c,
                    const float* __restrict__ Wih, const float* __restrict__ Whh,
                    const float* __restrict__ bih, const float* __restrict__ bhh)
{
    __shared__ __align__(16) float a_s[64][36];  // [kk][bl]
    __shared__ __align__(16) float b_s[64][72];  // [kk][nl]
    __shared__ __align__(16) float g_s[32][65];  // [bl][nl]

    int tid = threadIdx.x;           // 128
    int b0 = blockIdx.x * 32;
    int j0 = blockIdx.y * 16;
    int bg = tid & 7;                // b-group of 4
    int ng = tid >> 3;               // n-group of 4 (0..15)

    float acc[4][4] = {};

    for (int kc = 0; kc < 10; ++kc) {
        int Kbase = kc * 64;
        // A tile: 32 b x 64 k, transposed into a_s[kk][bl]
        #pragma unroll
        for (int i = 0; i < 16; ++i) {
            int idx = i * 128 + tid;
            int bl = idx >> 6, kk = idx & 63;
            int k = Kbase + kk;
            float v = (k < 128) ? gd[(b0 + bl) * Fd + k] : h_in[(b0 + bl) * Hd + (k - 128)];
            a_s[kk][bl] = v;
        }
        // B tile: 64 n x 64 k, transposed into b_s[kk][nl]; n = go*512 + j0 + jl
        #pragma unroll
        for (int i = 0; i < 32; ++i) {
            int idx = i * 128 + tid;
            int nl = idx >> 6, kk = idx & 63;
            int k = Kbase + kk;
            int n = (nl >> 4) * 512 + j0 + (nl & 15);
            float v = (k < 128) ? Wih[n * Fd + k] : Whh[n * Hd + (k - 128)];
            b_s[kk][nl] = v;
        }
        __syncthreads();
        #pragma unroll 4
        for (int kk = 0; kk < 64; ++kk) {
            float4 a4 = *(const float4*)&a_s[kk][bg * 4];
            float4 b4 = *(const float4*)&b_s[kk][ng * 4];
            float av[4] = {a4.x, a4.y, a4.z, a4.w};
            float bv[4] = {b4.x, b4.y, b4.z, b4.w};
            #pragma unroll
            for (int i = 0; i < 4; ++i)
                #pragma unroll
                for (int j = 0; j < 4; ++j)
                    acc[i][j] += av[i] * bv[j];
        }
        __syncthreads();
    }

    // stage gate pre-activations
    #pragma unroll
    for (int i = 0; i < 4; ++i)
        #pragma unroll
        for (int j = 0; j < 4; ++j)
            g_s[bg * 4 + i][ng * 4 + j] = acc[i][j];
    __syncthreads();

    // LSTM update: 512 (b,j) pairs, 4 per thread
    #pragma unroll
    for (int q = 0; q < 4; ++q) {
        int pid = q * 128 + tid;
        int bl = pid >> 4, jl = pid & 15;
        int b = b0 + bl, j = j0 + jl;
        float ig = g_s[bl][jl]      + bih[j]        + bhh[j];
        float fg = g_s[bl][16 + jl] + bih[512 + j]  + bhh[512 + j];
        float gg = g_s[bl][32 + jl] + bih[1024 + j] + bhh[1024 + j];
        float og = g_s[bl][48 + jl] + bih[1536 + j] + bhh[1536 + j];
        float cold = c[b * Hd + j];
        float cn = sigf(fg) * cold + sigf(ig) * tanhf(gg);
        float hn = sigf(og) * tanhf(cn);
        c[b * Hd + j] = cn;
        h_out[b * Hd + j] = hn;
    }
}

// final out = h_T @ Wfc^T + bfc
__global__ void kF(const float* __restrict__ h_in, const float* __restrict__ Wfc,
                   const float* __restrict__ bfc, float* __restrict__ out)
{
    __shared__ __align__(16) float h_s[Hd];
    int b = blockIdx.x, tid = threadIdx.x;   // 128
    h_s[tid]       = h_in[b * Hd + tid];
    h_s[tid + 128] = h_in[b * Hd + tid + 128];
    h_s[tid + 256] = h_in[b * Hd + tid + 256];
    h_s[tid + 384] = h_in[b * Hd + tid + 384];
    __syncthreads();
    float s = bfc[tid];
    const float4* w4 = (const float4*)(Wfc + tid * Hd);
    const float4* h4 = (const float4*)h_s;
    #pragma unroll 8
    for (int k = 0; k < 128; ++k) {
        float4 w = w4[k], h = h4[k];
        s += w.x * h.x + w.y * h.y + w.z * h.z + w.w * h.w;
    }
    out[b * Od + tid] = s;
}

extern "C" void kernel_launch(void* const* d_in, const int* in_sizes, int n_in,
                              void* d_out, int out_size, void* d_ws, size_t ws_size,
                              hipStream_t stream)
{
    const float* input = (const float*)d_in[0];
    const float* Xmean = (const float*)d_in[1];
    const float* Wgz   = (const float*)d_in[2];
    const float* bgz   = (const float*)d_in[3];
    const float* Wgzp  = (const float*)d_in[4];
    const float* bgzp  = (const float*)d_in[5];
    const float* Wq    = (const float*)d_in[6];
    const float* bq    = (const float*)d_in[7];
    const float* memory= (const float*)d_in[8];
    const float* Wih   = (const float*)d_in[9];
    const float* Whh   = (const float*)d_in[10];
    const float* bih   = (const float*)d_in[11];
    const float* bhh   = (const float*)d_in[12];
    const float* Wfc   = (const float*)d_in[13];
    const float* bfc   = (const float*)d_in[14];
    float* out = (float*)d_out;

    float* ws = (float*)d_ws;
    float* h0     = ws;                     // 256*512
    float* h1     = h0 + Bsz * Hd;          // 256*512
    float* c      = h1 + Bsz * Hd;          // 256*512
    float* gd     = c  + Bsz * Hd;          // 256*128
    float* WcombT = gd + Bsz * Fd;          // 128*512
    float* bqxi   = WcombT + Fd * Hd;       // 128

    hipMemsetAsync(h0, 0, Bsz * Hd * sizeof(float), stream);
    hipMemsetAsync(c,  0, Bsz * Hd * sizeof(float), stream);
    kA<<<257, 256, 0, stream>>>(Wfc, Wq, bfc, WcombT, bqxi);

    float* hb[2] = {h0, h1};
    for (int t = 0; t < Tn; ++t) {
        kS1<<<256, 256, 0, stream>>>(t, input, Xmean, Wgz, bgz, Wgzp, bgzp,
                                     Wq, bq, memory, WcombT, bqxi, hb[t & 1], gd);
        kS2<<<dim3(8, 32), 128, 0, stream>>>(gd, hb[t & 1], hb[(t + 1) & 1], c,
                                             Wih, Whh, bih, bhh);
    }
    kF<<<256, 128, 0, stream>>>(hb[0], Wfc, bfc, out);
}

// Round 3
// 10781.161 us; speedup vs baseline: 1.7541x; 1.7541x over previous
//
#include <hip/hip_runtime.h>
#include <hip/hip_cooperative_groups.h>
#include <cmath>

namespace cg = cooperative_groups;

#define Bsz 256
#define Tn  100
#define Fd  128
#define Hd  512
#define Od  128
#define Md  512

__device__ __forceinline__ float sigf(float x) { return 1.0f / (1.0f + __expf(-x)); }

// Precompute transposed/folded weights:
//  WlsT[k][f] (768x128): k<256 -> Wq[f][k]; k>=256 -> sum_o Wfc[o][k-256]*Wq[f][256+o]
//  bqs[f] = bq[f] + sum_o bfc[o]*Wq[f][256+o]
//  memT[f][m] = memory[m][f]   (128x512)
//  WfcT[j][f] = Wfc[f][j]      (512x128)
__global__ void kPre(const float* __restrict__ Wq, const float* __restrict__ bq,
                     const float* __restrict__ bfc, const float* __restrict__ Wfc,
                     const float* __restrict__ memory,
                     float* __restrict__ WlsT, float* __restrict__ memT,
                     float* __restrict__ WfcT, float* __restrict__ bqs)
{
    int bid = blockIdx.x, tid = threadIdx.x;
    if (bid < 768) {
        if (tid < 128) {
            int k = bid, f = tid;
            float v;
            if (k < 256) v = Wq[f * 384 + k];
            else {
                int kk = k - 256;
                float s = 0.f;
                for (int o = 0; o < 128; ++o) s += Wfc[o * 512 + kk] * Wq[f * 384 + 256 + o];
                v = s;
            }
            WlsT[k * 128 + f] = v;
        }
    } else if (bid == 768) {
        if (tid < 128) {
            float s = bq[tid];
            for (int o = 0; o < 128; ++o) s += bfc[o] * Wq[tid * 384 + 256 + o];
            bqs[tid] = s;
        }
    } else if (bid < 897) {
        int f = bid - 769;
        int m = tid;
        memT[f * 512 + m] = memory[m * 128 + f];
        m = tid + 256;
        memT[f * 512 + m] = memory[m * 128 + f];
    } else {
        int j = bid - 897;   // 0..511
        if (tid < 128) WfcT[j * 128 + tid] = Wfc[tid * 512 + j];
    }
}

// Persistent cooperative kernel: whole 100-step recurrence.
// 256 WGs x 256 threads (1 WG/CU). Per step:
//   phase A: WG b handles batch row b: zz -> ls -> scores -> softmax -> gd[b]
//   grid.sync()
//   phase B: WG (bb,cg): gates GEMM (64 rows x 32 gate-cols, K=640, W LDS-resident)
//            + fused LSTM update (c in registers), write h_next
//   grid.sync()
__launch_bounds__(256, 1)
__global__ void kMain(const float* __restrict__ input, const float* __restrict__ Xmean,
                      const float* __restrict__ Wgz, const float* __restrict__ bgz,
                      const float* __restrict__ Wgzp, const float* __restrict__ bgzp,
                      const float* __restrict__ memory,
                      const float* __restrict__ Wih, const float* __restrict__ Whh,
                      const float* __restrict__ bih, const float* __restrict__ bhh,
                      const float* __restrict__ bfc,
                      float* __restrict__ h0, float* __restrict__ h1,
                      float* __restrict__ gd,
                      const float* __restrict__ WlsT, const float* __restrict__ memT,
                      const float* __restrict__ WfcT, const float* __restrict__ bqs,
                      float* __restrict__ out)
{
    __shared__ __align__(16) float w_s[32 * 644];   // [nl][644] pad-4: 82.4 KB
    __shared__ __align__(16) float a_s[64 * 68];    // [bl][68] pad-4: 17.4 KB
    __shared__ __align__(16) float hs[512];
    __shared__ __align__(16) float zzs[256];
    __shared__ __align__(16) float lss[128];
    __shared__ __align__(16) float scs[512];
    __shared__ __align__(16) float red[1024];

    cg::grid_group grid = cg::this_grid();
    const int tid = threadIdx.x;
    const int wg  = blockIdx.x;

    // phase-B mapping: 4 batch-groups x 64 col-groups
    const int b0 = (wg >> 6) * 64;
    const int j0 = (wg & 63) * 8;
    const int ti = tid >> 4;        // 0..15 -> rows b0+4*ti..+4
    const int tj = tid & 15;        // 0..15 -> w rows {tj, tj+16}
    const int jl = tj & 7;
    const int jcol = j0 + jl;

    // load W slice into LDS (once)
    for (int idx = tid; idx < 32 * 644; idx += 256) {
        int nl = idx / 644, kk = idx - nl * 644;
        float v = 0.f;
        if (kk < 640) {
            int n = (nl >> 3) * 512 + j0 + (nl & 7);
            v = (kk < 128) ? Wih[n * 128 + kk] : Whh[n * 512 + (kk - 128)];
        }
        w_s[idx] = v;
    }
    const float bs0 = bih[0 * 512 + jcol] + bhh[0 * 512 + jcol];
    const float bs1 = bih[1 * 512 + jcol] + bhh[1 * 512 + jcol];
    const float bs2 = bih[2 * 512 + jcol] + bhh[2 * 512 + jcol];
    const float bs3 = bih[3 * 512 + jcol] + bhh[3 * 512 + jcol];
    float creg0 = 0.f, creg1 = 0.f;
    __syncthreads();

    const float4* WlsT4 = (const float4*)WlsT;
    const float4* memT4 = (const float4*)memT;
    const float4* mem4  = (const float4*)memory;
    const float4* bqs4  = (const float4*)bqs;
    float4* red4 = (float4*)red;
    float4* lss4 = (float4*)lss;
    float4* scs4 = (float4*)scs;
    float4* as4  = (float4*)a_s;
    const float4* ws4 = (const float4*)w_s;
    float4* gd4 = (float4*)gd;

    float* hcur = h0;
    float* hnxt = h1;

    for (int t = 0; t < Tn; ++t) {
        // ================= phase A (row b = wg) =================
        {
            const int b = wg;
            hs[tid]       = hcur[b * 512 + tid];
            hs[tid + 256] = hcur[b * 512 + tid + 256];
            {
                int f = tid & 127;
                const float* basep = input + (size_t)b * 6 * Tn * Fd + t * Fd;
                float x    = basep[0 * Tn * Fd + f];
                float mask = basep[2 * Tn * Fd + f];
                float xm   = Xmean[t * Fd + f];
                float xl, dl, wv, bv;
                if (tid < 128) { xl = basep[1 * Tn * Fd + f]; dl = basep[3 * Tn * Fd + f]; wv = Wgz[f * 129];  bv = bgz[f]; }
                else           { xl = basep[4 * Tn * Fd + f]; dl = basep[5 * Tn * Fd + f]; wv = Wgzp[f * 129]; bv = bgzp[f]; }
                float d = __expf(-fmaxf(dl * wv + bv, 0.f));
                zzs[tid] = mask * x + (1.f - mask) * (d * xl + (1.f - d) * xm);
            }
            __syncthreads();
            // ls partials: k in [kh*96, +96) of 768 (256 zz + 512 h)
            {
                int fg = tid & 31, kh = tid >> 5;
                float4 acc = {0.f, 0.f, 0.f, 0.f};
                int ks = kh * 96;
                #pragma unroll 8
                for (int kk = 0; kk < 96; ++kk) {
                    int k = ks + kk;
                    float v = (k < 256) ? zzs[k] : hs[k - 256];
                    float4 w = WlsT4[k * 32 + fg];
                    acc.x += v * w.x; acc.y += v * w.y; acc.z += v * w.z; acc.w += v * w.w;
                }
                red4[kh * 32 + fg] = acc;
            }
            __syncthreads();
            if (tid < 32) {
                float4 s = bqs4[tid];
                #pragma unroll
                for (int kh = 0; kh < 8; ++kh) {
                    float4 r = red4[kh * 32 + tid];
                    s.x += r.x; s.y += r.y; s.z += r.z; s.w += r.w;
                }
                lss4[tid] = s;
            }
            __syncthreads();
            // scores
            {
                int mg = tid & 127, fh = tid >> 7;
                float4 acc = {0.f, 0.f, 0.f, 0.f};
                int fs = fh * 64;
                #pragma unroll 8
                for (int ff = 0; ff < 64; ++ff) {
                    float v = lss[fs + ff];
                    float4 w = memT4[(fs + ff) * 128 + mg];
                    acc.x += v * w.x; acc.y += v * w.y; acc.z += v * w.z; acc.w += v * w.w;
                }
                red4[fh * 128 + mg] = acc;
            }
            __syncthreads();
            if (tid < 128) {
                float4 a = red4[tid], bv = red4[128 + tid];
                float4 s = {a.x + bv.x, a.y + bv.y, a.z + bv.z, a.w + bv.w};
                scs4[tid] = s;
            }
            __syncthreads();
            // softmax over 512
            float v0 = scs[tid], v1 = scs[tid + 256];
            float mv = fmaxf(v0, v1);
            #pragma unroll
            for (int off = 32; off > 0; off >>= 1) mv = fmaxf(mv, __shfl_xor(mv, off));
            if ((tid & 63) == 0) red[tid >> 6] = mv;
            __syncthreads();
            float mx = fmaxf(fmaxf(red[0], red[1]), fmaxf(red[2], red[3]));
            float e0 = __expf(v0 - mx), e1 = __expf(v1 - mx);
            __syncthreads();           // red[0..3] consumed; safe to reuse
            scs[tid] = e0; scs[tid + 256] = e1;
            float sv = e0 + e1;
            #pragma unroll
            for (int off = 32; off > 0; off >>= 1) sv += __shfl_xor(sv, off);
            if ((tid & 63) == 0) red[tid >> 6] = sv;
            __syncthreads();
            float inv = 1.f / (red[0] + red[1] + red[2] + red[3]);
            // gd = attn @ memory
            {
                int fg = tid & 31, mh = tid >> 5;
                float4 acc = {0.f, 0.f, 0.f, 0.f};
                int ms = mh * 64;
                #pragma unroll 8
                for (int mm = 0; mm < 64; ++mm) {
                    float p = scs[ms + mm];
                    float4 w = mem4[(ms + mm) * 32 + fg];
                    acc.x += p * w.x; acc.y += p * w.y; acc.z += p * w.z; acc.w += p * w.w;
                }
                __syncthreads();       // inv/scs reads done; reuse red
                red4[mh * 32 + fg] = acc;
            }
            __syncthreads();
            if (tid < 32) {
                float4 s = {0.f, 0.f, 0.f, 0.f};
                #pragma unroll
                for (int kh = 0; kh < 8; ++kh) {
                    float4 r = red4[kh * 32 + tid];
                    s.x += r.x; s.y += r.y; s.z += r.z; s.w += r.w;
                }
                s.x *= inv; s.y *= inv; s.z *= inv; s.w *= inv;
                gd4[wg * 32 + tid] = s;
            }
        }
        grid.sync();
        // ================= phase B =================
        {
            const float4* gdc4 = (const float4*)gd;
            const float4* h4   = (const float4*)hcur;
            float4 pf[4];
            #pragma unroll
            for (int ii = 0; ii < 4; ++ii) {
                int f4i = ii * 256 + tid;
                int bl = f4i >> 4, kq = f4i & 15;
                pf[ii] = gdc4[(b0 + bl) * 32 + kq];     // chunk 0 (k-quads 0..15)
            }
            float acc[4][2] = {};
            for (int kc = 0; kc < 10; ++kc) {
                #pragma unroll
                for (int ii = 0; ii < 4; ++ii) {
                    int f4i = ii * 256 + tid;
                    int bl = f4i >> 4, kq = f4i & 15;
                    as4[bl * 17 + kq] = pf[ii];
                }
                __syncthreads();
                if (kc < 9) {
                    int kcn = kc + 1;
                    #pragma unroll
                    for (int ii = 0; ii < 4; ++ii) {
                        int f4i = ii * 256 + tid;
                        int bl = f4i >> 4, kq = f4i & 15;
                        pf[ii] = (kcn < 2) ? gdc4[(b0 + bl) * 32 + kcn * 16 + kq]
                                           : h4[(b0 + bl) * 128 + (kcn - 2) * 16 + kq];
                    }
                }
                #pragma unroll 4
                for (int kq = 0; kq < 16; ++kq) {
                    float4 w0 = ws4[tj * 161 + kc * 16 + kq];
                    float4 w1 = ws4[(tj + 16) * 161 + kc * 16 + kq];
                    #pragma unroll
                    for (int c = 0; c < 4; ++c) {
                        float4 a = as4[(ti * 4 + c) * 17 + kq];
                        acc[c][0] += a.x * w0.x + a.y * w0.y + a.z * w0.z + a.w * w0.w;
                        acc[c][1] += a.x * w1.x + a.y * w1.y + a.z * w1.z + a.w * w1.w;
                    }
                }
                __syncthreads();
            }
            // LSTM epilogue: exchange complementary gates with lane^8
            float p0[4], p1[4];
            #pragma unroll
            for (int c = 0; c < 4; ++c) {
                p0[c] = __shfl_xor(acc[c][0], 8);
                p1[c] = __shfl_xor(acc[c][1], 8);
            }
            const bool lo = (tj < 8);
            #pragma unroll
            for (int rr = 0; rr < 2; ++rr) {
                int cc = lo ? rr : (rr + 2);
                float gi = lo ? acc[rr][0] : p0[rr + 2];
                float gf = lo ? p0[rr]     : acc[rr + 2][0];
                float gg = lo ? acc[rr][1] : p1[rr + 2];
                float go = lo ? p1[rr]     : acc[rr + 2][1];
                gi += bs0; gf += bs1; gg += bs2; go += bs3;
                float cold = (rr == 0) ? creg0 : creg1;
                float cn = sigf(gf) * cold + sigf(gi) * tanhf(gg);
                float hn = sigf(go) * tanhf(cn);
                if (rr == 0) creg0 = cn; else creg1 = cn;
                hnxt[(b0 + ti * 4 + cc) * 512 + jcol] = hn;
            }
        }
        grid.sync();
        float* tsw = hcur; hcur = hnxt; hnxt = tsw;
    }

    // ================= final out = h @ WfcT + bfc =================
    {
        const int b = wg;
        hs[tid]       = hcur[b * 512 + tid];
        hs[tid + 256] = hcur[b * 512 + tid + 256];
        __syncthreads();
        int fg = tid & 31, jh = tid >> 5;
        const float4* WfcT4 = (const float4*)WfcT;
        float4 acc = {0.f, 0.f, 0.f, 0.f};
        int js = jh * 64;
        #pragma unroll 8
        for (int jj = 0; jj < 64; ++jj) {
            float hv = hs[js + jj];
            float4 w = WfcT4[(js + jj) * 32 + fg];
            acc.x += hv * w.x; acc.y += hv * w.y; acc.z += hv * w.z; acc.w += hv * w.w;
        }
        red4[jh * 32 + fg] = acc;
        __syncthreads();
        if (tid < 32) {
            const float4* bfc4 = (const float4*)bfc;
            float4 s = bfc4[tid];
            #pragma unroll
            for (int kh = 0; kh < 8; ++kh) {
                float4 r = red4[kh * 32 + tid];
                s.x += r.x; s.y += r.y; s.z += r.z; s.w += r.w;
            }
            ((float4*)out)[b * 32 + tid] = s;
        }
    }
}

extern "C" void kernel_launch(void* const* d_in, const int* in_sizes, int n_in,
                              void* d_out, int out_size, void* d_ws, size_t ws_size,
                              hipStream_t stream)
{
    const float* input  = (const float*)d_in[0];
    const float* Xmean  = (const float*)d_in[1];
    const float* Wgz    = (const float*)d_in[2];
    const float* bgz    = (const float*)d_in[3];
    const float* Wgzp   = (const float*)d_in[4];
    const float* bgzp   = (const float*)d_in[5];
    const float* Wq     = (const float*)d_in[6];
    const float* bq     = (const float*)d_in[7];
    const float* memory = (const float*)d_in[8];
    const float* Wih    = (const float*)d_in[9];
    const float* Whh    = (const float*)d_in[10];
    const float* bih    = (const float*)d_in[11];
    const float* bhh    = (const float*)d_in[12];
    const float* Wfc    = (const float*)d_in[13];
    const float* bfc    = (const float*)d_in[14];
    float* outp = (float*)d_out;

    float* ws   = (float*)d_ws;
    float* h0   = ws;                 // 131072
    float* h1   = h0 + 131072;        // 131072
    float* gdp  = h1 + 131072;        // 32768
    float* WlsT = gdp + 32768;        // 98304
    float* memT = WlsT + 98304;       // 65536
    float* WfcT = memT + 65536;       // 65536
    float* bqs  = WfcT + 65536;       // 128

    hipMemsetAsync(h0, 0, 131072 * sizeof(float), stream);
    kPre<<<1409, 256, 0, stream>>>(Wq, bq, bfc, Wfc, memory, WlsT, memT, WfcT, bqs);

    void* args[] = {
        (void*)&input, (void*)&Xmean, (void*)&Wgz, (void*)&bgz, (void*)&Wgzp, (void*)&bgzp,
        (void*)&memory, (void*)&Wih, (void*)&Whh, (void*)&bih, (void*)&bhh, (void*)&bfc,
        (void*)&h0, (void*)&h1, (void*)&gdp, (void*)&WlsT, (void*)&memT, (void*)&WfcT,
        (void*)&bqs, (void*)&outp
    };
    hipLaunchCooperativeKernel((void*)kMain, dim3(256), dim3(256), args, 0, stream);
}